// Round 1
// baseline (567.861 us; speedup 1.0000x reference)
//
#include <hip/hip_runtime.h>
#include <cstdint>
#include <cstddef>

#define HEADS 4
#define HC 64
#define INC 128
#define OC 16
#define NEG 0.2f

// ---------------- GEMM1: X[N,128] @ W1[128,256] -> H1[N,256] ----------------
__global__ __launch_bounds__(256) void k_gemm1(const float* __restrict__ X,
                                               const float* __restrict__ W,
                                               float* __restrict__ H, int N) {
  __shared__ float Ast[64][68];  // [k][row], transposed A half-tile
  __shared__ float Bs[64][64];   // [k][col]
  int t = threadIdx.x;
  int rb = blockIdx.x * 64, cb = blockIdx.y * 64;
  int tx = t & 15, ty = t >> 4;
  float acc[4][4] = {{0.f, 0.f, 0.f, 0.f}, {0.f, 0.f, 0.f, 0.f},
                     {0.f, 0.f, 0.f, 0.f}, {0.f, 0.f, 0.f, 0.f}};
  for (int kb = 0; kb < 128; kb += 64) {
    // stage A: X[rb..rb+63][kb..kb+63], transposed into Ast[k][row]
    #pragma unroll
    for (int i = 0; i < 4; i++) {
      int id = t * 4 + i * 1024;          // 0..4095
      int r = id >> 6, c = id & 63;
      int gr = rb + r; if (gr >= N) gr = N - 1;
      float4 v = *(const float4*)(X + (size_t)gr * 128 + kb + c);
      Ast[c + 0][r] = v.x; Ast[c + 1][r] = v.y;
      Ast[c + 2][r] = v.z; Ast[c + 3][r] = v.w;
    }
    // stage B: W[kb..kb+63][cb..cb+63]
    #pragma unroll
    for (int i = 0; i < 4; i++) {
      int id = t * 4 + i * 1024;
      int r = id >> 6, c = id & 63;
      float4 v = *(const float4*)(W + (size_t)(kb + r) * 256 + cb + c);
      *(float4*)(&Bs[r][c]) = v;
    }
    __syncthreads();
    #pragma unroll 8
    for (int k = 0; k < 64; k++) {
      float4 a = *(const float4*)(&Ast[k][ty * 4]);
      float4 b = *(const float4*)(&Bs[k][tx * 4]);
      acc[0][0] += a.x * b.x; acc[0][1] += a.x * b.y; acc[0][2] += a.x * b.z; acc[0][3] += a.x * b.w;
      acc[1][0] += a.y * b.x; acc[1][1] += a.y * b.y; acc[1][2] += a.y * b.z; acc[1][3] += a.y * b.w;
      acc[2][0] += a.z * b.x; acc[2][1] += a.z * b.y; acc[2][2] += a.z * b.z; acc[2][3] += a.z * b.w;
      acc[3][0] += a.w * b.x; acc[3][1] += a.w * b.y; acc[3][2] += a.w * b.z; acc[3][3] += a.w * b.w;
    }
    __syncthreads();
  }
  #pragma unroll
  for (int i = 0; i < 4; i++) {
    int gr = rb + ty * 4 + i;
    if (gr < N) {
      float4 v = make_float4(acc[i][0], acc[i][1], acc[i][2], acc[i][3]);
      *(float4*)(H + (size_t)gr * 256 + cb + tx * 4) = v;
    }
  }
}

// ------------- attention logits per node, layer 1: al_s/al_d [N,4] ----------
__global__ __launch_bounds__(256) void k_al1(const float* __restrict__ H,
                                             const float* __restrict__ asrc,
                                             const float* __restrict__ adst,
                                             float* __restrict__ als,
                                             float* __restrict__ ald, int N) {
  int n = blockIdx.x;
  int t = threadIdx.x;
  int h = t >> 6, c = t & 63;
  float v = H[(size_t)n * 256 + t];
  float ps = v * asrc[t];  // att_src1 flat (4,64)
  float pd = v * adst[t];
  #pragma unroll
  for (int off = 32; off > 0; off >>= 1) {
    ps += __shfl_down(ps, off);
    pd += __shfl_down(pd, off);
  }
  if (c == 0) { als[n * 4 + h] = ps; ald[n * 4 + h] = pd; }
}

// ------------- per-edge scores layer1 + degree count ------------------------
__global__ void k_score_deg1(const int* __restrict__ ei,
                             const float* __restrict__ als,
                             const float* __restrict__ ald,
                             float* __restrict__ sc, int* __restrict__ deg,
                             int E, int ET) {
  int e = blockIdx.x * 256 + threadIdx.x;
  if (e >= ET) return;
  int s, d;
  if (e < E) { s = ei[e]; d = ei[E + e]; } else { s = d = e - E; }
  float4 a = *(const float4*)(als + (size_t)s * 4);
  float4 b = *(const float4*)(ald + (size_t)d * 4);
  float4 o;
  o.x = a.x + b.x; o.y = a.y + b.y; o.z = a.z + b.z; o.w = a.w + b.w;
  o.x = o.x > 0.f ? o.x : NEG * o.x;
  o.y = o.y > 0.f ? o.y : NEG * o.y;
  o.z = o.z > 0.f ? o.z : NEG * o.z;
  o.w = o.w > 0.f ? o.w : NEG * o.w;
  *(float4*)(sc + (size_t)e * 4) = o;
  atomicAdd(&deg[d], 1);
}

// ------------------------------- scan (3 kernels) ---------------------------
__global__ __launch_bounds__(256) void k_scan_partial(const int* __restrict__ deg,
                                                      int* __restrict__ bsum, int N) {
  __shared__ int sd[256];
  int t = threadIdx.x;
  int base = blockIdx.x * 1024 + t * 4;
  int s = 0;
  #pragma unroll
  for (int j = 0; j < 4; j++) { int i = base + j; s += (i < N) ? deg[i] : 0; }
  sd[t] = s;
  __syncthreads();
  for (int o = 128; o > 0; o >>= 1) {
    if (t < o) sd[t] += sd[t + o];
    __syncthreads();
  }
  if (t == 0) bsum[blockIdx.x] = sd[0];
}

__global__ void k_scan_sums(const int* __restrict__ bsum, int* __restrict__ boff,
                            int* __restrict__ offsets, int NB, int N) {
  if (threadIdx.x == 0 && blockIdx.x == 0) {
    int run = 0;
    for (int i = 0; i < NB; i++) { boff[i] = run; run += bsum[i]; }
    offsets[N] = run;
  }
}

__global__ __launch_bounds__(256) void k_scan_final(const int* __restrict__ deg,
                                                    const int* __restrict__ boff,
                                                    int* __restrict__ offsets,
                                                    int* __restrict__ cursor, int N) {
  __shared__ int sd[256];
  int t = threadIdx.x;
  int base = blockIdx.x * 1024 + t * 4;
  int v[4]; int s = 0;
  #pragma unroll
  for (int j = 0; j < 4; j++) { int i = base + j; v[j] = (i < N) ? deg[i] : 0; s += v[j]; }
  int my = s;
  sd[t] = s;
  __syncthreads();
  for (int o = 1; o < 256; o <<= 1) {
    int add = (t >= o) ? sd[t - o] : 0;
    __syncthreads();
    sd[t] += add;
    __syncthreads();
  }
  int run = sd[t] - my + boff[blockIdx.x];
  #pragma unroll
  for (int j = 0; j < 4; j++) {
    int i = base + j;
    if (i < N) { offsets[i] = run; cursor[i] = run; run += v[j]; }
  }
}

// ------------------------------- CSR fill -----------------------------------
__global__ void k_fill(const int* __restrict__ ei, int* __restrict__ cursor,
                       int2* __restrict__ csr, int E, int ET) {
  int e = blockIdx.x * 256 + threadIdx.x;
  if (e >= ET) return;
  int s, d;
  if (e < E) { s = ei[e]; d = ei[E + e]; } else { s = d = e - E; }
  int pos = atomicAdd(&cursor[d], 1);
  csr[pos] = make_int2(s, e);
}

// -------- layer1 aggregation: segment softmax + SpMM + bias + ReLU ----------
__global__ __launch_bounds__(256) void k_agg1(const int* __restrict__ off,
                                              const int2* __restrict__ csr,
                                              const float* __restrict__ sc,
                                              const float* __restrict__ H,
                                              const float* __restrict__ b1,
                                              float* __restrict__ H2, int N) {
  int n = blockIdx.x;
  int t = threadIdx.x;
  int h = t >> 6;
  int st = off[n], en = off[n + 1];
  float m = -1e30f;
  for (int i = st; i < en; i++) {
    int eid = csr[i].y;
    m = fmaxf(m, sc[(size_t)eid * 4 + h]);
  }
  float s = 0.f, acc = 0.f;
  for (int i = st; i < en; i++) {
    int2 ce = csr[i];
    float p = __expf(sc[(size_t)ce.y * 4 + h] - m);
    s += p;
    acc += p * H[(size_t)ce.x * 256 + t];
  }
  float v = acc / (s + 1e-16f) + b1[t];
  H2[(size_t)n * 256 + t] = fmaxf(v, 0.f);
}

// ------- layer2 GEMM (256->16) + attention-logit dots, fused ----------------
__global__ __launch_bounds__(256) void k_gemm2(const float* __restrict__ H2,
                                               const float* __restrict__ W2,
                                               const float* __restrict__ as2,
                                               const float* __restrict__ ad2,
                                               float* __restrict__ Z,
                                               float* __restrict__ als2,
                                               float* __restrict__ ald2, int N) {
  __shared__ float w2s[4096];  // 256x16
  int t = threadIdx.x;
  for (int i = t; i < 4096; i += 256) w2s[i] = W2[i];
  __syncthreads();
  int n = blockIdx.x * 16 + (t >> 4);
  int c = t & 15;
  if (n >= N) return;
  const float* hp = H2 + (size_t)n * 256;
  float acc = 0.f;
  #pragma unroll 8
  for (int k = 0; k < 256; k += 4) {
    float4 hv = *(const float4*)(hp + k);
    acc += hv.x * w2s[(k + 0) * 16 + c];
    acc += hv.y * w2s[(k + 1) * 16 + c];
    acc += hv.z * w2s[(k + 2) * 16 + c];
    acc += hv.w * w2s[(k + 3) * 16 + c];
  }
  Z[(size_t)n * 16 + c] = acc;
  float ps = acc * as2[c], pd = acc * ad2[c];
  #pragma unroll
  for (int o = 8; o > 0; o >>= 1) {
    ps += __shfl_down(ps, o, 16);
    pd += __shfl_down(pd, o, 16);
  }
  if (c == 0) { als2[n] = ps; ald2[n] = pd; }
}

// ------------- per-edge scores layer 2 --------------------------------------
__global__ void k_score2(const int* __restrict__ ei, const float* __restrict__ als2,
                         const float* __restrict__ ald2, float* __restrict__ sc2,
                         int E, int ET) {
  int e = blockIdx.x * 256 + threadIdx.x;
  if (e >= ET) return;
  int s, d;
  if (e < E) { s = ei[e]; d = ei[E + e]; } else { s = d = e - E; }
  float v = als2[s] + ald2[d];
  sc2[e] = v > 0.f ? v : NEG * v;
}

// ---- layer2 aggregation + bias + log_softmax, 16 threads per node ----------
__global__ __launch_bounds__(256) void k_agg2(const int* __restrict__ off,
                                              const int2* __restrict__ csr,
                                              const float* __restrict__ sc2,
                                              const float* __restrict__ Z,
                                              const float* __restrict__ b2,
                                              float* __restrict__ out, int N) {
  int t = threadIdx.x;
  int n = blockIdx.x * 16 + (t >> 4);
  int c = t & 15;
  if (n >= N) return;
  int st = off[n], en = off[n + 1];
  float m = -1e30f;
  for (int i = st; i < en; i++) m = fmaxf(m, sc2[csr[i].y]);
  float s = 0.f, acc = 0.f;
  for (int i = st; i < en; i++) {
    int2 ce = csr[i];
    float p = __expf(sc2[ce.y] - m);
    s += p;
    acc += p * Z[(size_t)ce.x * 16 + c];
  }
  float v = acc / (s + 1e-16f) + b2[c];
  // log_softmax over the 16 lanes of this node
  float mx = v;
  #pragma unroll
  for (int o = 8; o > 0; o >>= 1) mx = fmaxf(mx, __shfl_xor(mx, o, 16));
  float ex = __expf(v - mx);
  float sm = ex;
  #pragma unroll
  for (int o = 8; o > 0; o >>= 1) sm += __shfl_xor(sm, o, 16);
  out[(size_t)n * 16 + c] = v - mx - logf(sm);
}

extern "C" void kernel_launch(void* const* d_in, const int* in_sizes, int n_in,
                              void* d_out, int out_size, void* d_ws, size_t ws_size,
                              hipStream_t stream) {
  const float* x   = (const float*)d_in[0];
  const int*   ei  = (const int*)d_in[1];
  const float* W1  = (const float*)d_in[2];
  const float* as1 = (const float*)d_in[3];
  const float* ad1 = (const float*)d_in[4];
  const float* b1  = (const float*)d_in[5];
  const float* W2  = (const float*)d_in[6];
  const float* as2 = (const float*)d_in[7];
  const float* ad2 = (const float*)d_in[8];
  const float* b2  = (const float*)d_in[9];
  float* out = (float*)d_out;

  int N  = in_sizes[0] / INC;   // 50000
  int E  = in_sizes[1] / 2;     // 800000
  int ET = E + N;               // + self loops
  int NB = (N + 1023) / 1024;

  char* w = (char*)d_ws;
  size_t off_b = 0;
  auto alloc = [&](size_t bytes) -> char* {
    size_t start = (off_b + 255) & ~(size_t)255;
    off_b = start + bytes;
    return w + start;
  };
  float* h1   = (float*)alloc((size_t)N * 256 * 4);
  float* h2   = (float*)alloc((size_t)N * 256 * 4);
  float* als1 = (float*)alloc((size_t)N * 4 * 4);
  float* ald1 = (float*)alloc((size_t)N * 4 * 4);
  float* sc1  = (float*)alloc((size_t)ET * 4 * 4);
  int*   deg  = (int*)alloc((size_t)N * 4);
  int*   offs = (int*)alloc((size_t)(N + 1) * 4);
  int*   cur  = (int*)alloc((size_t)N * 4);
  int*   bsum = (int*)alloc((size_t)NB * 4);
  int*   boff = (int*)alloc((size_t)NB * 4);
  int2*  csr  = (int2*)alloc((size_t)ET * 8);
  float* z    = (float*)alloc((size_t)N * 16 * 4);
  float* als2 = (float*)alloc((size_t)N * 4);
  float* ald2 = (float*)alloc((size_t)N * 4);
  float* sc2  = (float*)alloc((size_t)ET * 4);

  hipMemsetAsync(deg, 0, (size_t)N * 4, stream);
  k_gemm1<<<dim3((N + 63) / 64, 4), 256, 0, stream>>>(x, W1, h1, N);
  k_al1<<<N, 256, 0, stream>>>(h1, as1, ad1, als1, ald1, N);
  k_score_deg1<<<(ET + 255) / 256, 256, 0, stream>>>(ei, als1, ald1, sc1, deg, E, ET);
  k_scan_partial<<<NB, 256, 0, stream>>>(deg, bsum, N);
  k_scan_sums<<<1, 1, 0, stream>>>(bsum, boff, offs, NB, N);
  k_scan_final<<<NB, 256, 0, stream>>>(deg, boff, offs, cur, N);
  k_fill<<<(ET + 255) / 256, 256, 0, stream>>>(ei, cur, csr, E, ET);
  k_agg1<<<N, 256, 0, stream>>>(offs, csr, sc1, h1, b1, h2, N);
  k_gemm2<<<(N + 15) / 16, 256, 0, stream>>>(h2, W2, as2, ad2, z, als2, ald2, N);
  k_score2<<<(ET + 255) / 256, 256, 0, stream>>>(ei, als2, ald2, sc2, E, ET);
  k_agg2<<<(N + 15) / 16, 256, 0, stream>>>(offs, csr, sc2, z, b2, out, N);
}